// Round 14
// baseline (181.616 us; speedup 1.0000x reference)
//
#include <hip/hip_runtime.h>
#include <stdint.h>

// r13 passed (absmax 7.6e-6) but dur identical to r12 (198.4us) despite -30%
// threefry calls => invariant bottleneck. VGPR_Count=16 (impossibly low) in
// both rounds points at rule #20: the rotA/rotB/ks locals with loop-variable
// indexing + pointer-select likely demoted to scratch -> ~25 scratch accesses
// per threefry call, state spilled, VALU starved.
// THIS ROUND (single variable): macro-expanded threefry, literal rotations,
// ZERO local arrays / runtime indexing. Everything else identical to r13.
// Transcendentals remain raw-ISA inline asm (libm compile hangs on this pod).

__device__ __forceinline__ float fast_log2(float x) {
  float r; asm("v_log_f32 %0, %1" : "=v"(r) : "v"(x)); return r;
}
__device__ __forceinline__ float fast_exp2(float x) {
  float r; asm("v_exp_f32 %0, %1" : "=v"(r) : "v"(x)); return r;
}
__device__ __forceinline__ float fast_tanh(float w) {  // (t-1)/(t+1), t=e^2w
  float t = fast_exp2(w * 2.8853900817779268f);
  return (t - 1.0f) / (t + 1.0f);
}

__device__ __forceinline__ uint32_t rotl(uint32_t x, int r) {
  return __builtin_rotateleft32(x, (unsigned)r);
}

// Fully expanded threefry2x32: no arrays, no runtime indexing anywhere.
__device__ __forceinline__ void threefry2x32(uint32_t k0, uint32_t k1,
                                             uint32_t x0, uint32_t x1,
                                             uint32_t& o0, uint32_t& o1) {
  const uint32_t ks2 = k0 ^ k1 ^ 0x1BD11BDAu;
  x0 += k0; x1 += k1;
#define TF_RND(r) { x0 += x1; x1 = rotl(x1, (r)); x1 ^= x0; }
  TF_RND(13) TF_RND(15) TF_RND(26) TF_RND(6)
  x0 += k1;  x1 += ks2 + 1u;
  TF_RND(17) TF_RND(29) TF_RND(16) TF_RND(24)
  x0 += ks2; x1 += k0 + 2u;
  TF_RND(13) TF_RND(15) TF_RND(26) TF_RND(6)
  x0 += k0;  x1 += k1 + 3u;
  TF_RND(17) TF_RND(29) TF_RND(16) TF_RND(24)
  x0 += k1;  x1 += ks2 + 4u;
  TF_RND(13) TF_RND(15) TF_RND(26) TF_RND(6)
  x0 += ks2; x1 += k0 + 5u;
#undef TF_RND
  o0 = x0; o1 = x1;
}

__device__ __forceinline__ uint32_t tf_bits(uint32_t ka, uint32_t kb, uint32_t e) {
  uint32_t r0, r1;
  threefry2x32(ka, kb, 0u, e, r0, r1);
  return r0 ^ r1;
}

// l2 = log2(max(-log2(u), 1e-37)), u = frac-from-bits + tiny (NaN-guarded)
__device__ __forceinline__ float neglog2_from_bits(uint32_t bits) {
  float f  = __uint_as_float((bits >> 9) | 0x3f800000u) - 1.0f;
  float u  = f + 1.17549435e-38f;
  float l1 = fast_log2(u);
  float nl = fmaxf(-l1, 1e-37f);
  return fast_log2(nl);
}

// grid: 2048 blocks = 512 o x 4 bgroups; 256 threads (4 waves); 16 rows/wave.
__global__ __launch_bounds__(256) void k_fused(const float* __restrict__ x,
                                               const float* __restrict__ weight,
                                               const float* __restrict__ logits,
                                               float* __restrict__ out) {
  const int o    = blockIdx.x & 511;
  const int bg   = blockIdx.x >> 9;   // 0..3
  const int tid  = threadIdx.x;
  const int lane = tid & 63;
  const int wid  = tid >> 6;
  const float* lrow = logits + o * 512;

  // subkeys (fold-like split of key(42) = (0,42))
  uint32_t k1a, k1b, k2a, k2b;
  threefry2x32(0u, 42u, 0u, 0u, k1a, k1b);  // kg1 for g1 (OUT,IN)
  threefry2x32(0u, 42u, 0u, 1u, k2a, k2b);  // kg2 for g2 (B,OUT,IN)

  // ---- phase 1 (block-cooperative): i* = argmax_i(logits[o,i] + g1[o,i]) ----
  float v; int idx;
  {
    const uint32_t e0 = (uint32_t)(o * 512 + tid);
    float g1a = fmaf(-0.69314718056f, neglog2_from_bits(tf_bits(k1a, k1b, e0)),
                     0.3665129206f);
    v   = lrow[tid] + g1a;
    idx = tid;
    float g1b = fmaf(-0.69314718056f, neglog2_from_bits(tf_bits(k1a, k1b, e0 + 256u)),
                     0.3665129206f);
    float v2 = lrow[tid + 256] + g1b;
    if (v2 > v) { v = v2; idx = tid + 256; }  // tie -> lower index (jnp.argmax)
  }
  for (int off = 32; off > 0; off >>= 1) {
    float ov = __shfl_down(v, off);
    int   oi = __shfl_down(idx, off);
    if (ov > v || (ov == v && oi < idx)) { v = ov; idx = oi; }
  }
  __shared__ float swv[4];
  __shared__ int   swi[4];
  __shared__ int   s_istar;
  __shared__ float s_c;
  if (lane == 0) { swv[wid] = v; swi[wid] = idx; }
  __syncthreads();
  if (tid == 0) {
    float bv = swv[0]; int bi = swi[0];
    for (int w = 1; w < 4; ++w)
      if (swv[w] > bv || (swv[w] == bv && swi[w] < bi)) { bv = swv[w]; bi = swi[w]; }
    s_istar = bi;
    s_c = 2.0f * fast_tanh(2.0f * fast_tanh(weight[o * 512 + bi]));
  }
  __syncthreads();
  const int   isel = s_istar;
  const float c    = s_c;

  // ---- cache scaled logits for this o (block-constant) in registers ----
  // ev = exp2(lsc[j] - l2), lsc = l*log2e - log2(ln2)
  float lsc0 = fmaf(lrow[lane      ], 1.4426950408889634f, 0.5287663729f);
  float lsc1 = fmaf(lrow[lane +  64], 1.4426950408889634f, 0.5287663729f);
  float lsc2 = fmaf(lrow[lane + 128], 1.4426950408889634f, 0.5287663729f);
  float lsc3 = fmaf(lrow[lane + 192], 1.4426950408889634f, 0.5287663729f);
  float lsc4 = fmaf(lrow[lane + 256], 1.4426950408889634f, 0.5287663729f);
  float lsc5 = fmaf(lrow[lane + 320], 1.4426950408889634f, 0.5287663729f);
  float lsc6 = fmaf(lrow[lane + 384], 1.4426950408889634f, 0.5287663729f);
  float lsc7 = fmaf(lrow[lane + 448], 1.4426950408889634f, 0.5287663729f);

  // ---- phase 2: 16 rows per wave ----
  const int b0 = bg * 64 + wid * 16;
#pragma unroll 1
  for (int it = 0; it < 16; ++it) {
    const int b   = b0 + it;                   // 0..255
    const int row = (b << 9) | o;              // 0..131071
    const uint32_t base = (uint32_t)row << 9;  // < 2^26

    float sum = 0.0f, selv = 0.0f;
#define G2_SAMPLE(J, LSC)                                                  \
    {                                                                      \
      const int i = lane + 64 * (J);                                       \
      float l2 = neglog2_from_bits(tf_bits(k2a, k2b, base + (uint32_t)i)); \
      float ev = fast_exp2((LSC) - l2);                                    \
      sum += ev;                                                           \
      selv = (i == isel) ? ev : selv;                                      \
    }
    G2_SAMPLE(0, lsc0) G2_SAMPLE(1, lsc1) G2_SAMPLE(2, lsc2) G2_SAMPLE(3, lsc3)
    G2_SAMPLE(4, lsc4) G2_SAMPLE(5, lsc5) G2_SAMPLE(6, lsc6) G2_SAMPLE(7, lsc7)
#undef G2_SAMPLE
    for (int off = 32; off > 0; off >>= 1) sum += __shfl_down(sum, off);
    selv = __shfl(selv, isel & 63);            // exactly one lane holds it
    if (lane == 0) out[row] = c * x[(b << 9) | isel] * selv / sum;
  }
}

extern "C" void kernel_launch(void* const* d_in, const int* in_sizes, int n_in,
                              void* d_out, int out_size, void* d_ws, size_t ws_size,
                              hipStream_t stream) {
  const float* x      = (const float*)d_in[0];
  const float* weight = (const float*)d_in[1];
  const float* logits = (const float*)d_in[2];
  float* out = (float*)d_out;
  k_fused<<<dim3(512 * 4), dim3(256), 0, stream>>>(x, weight, logits, out);
}

// Round 15
// 181.052 us; speedup vs baseline: 1.0031x; 1.0031x over previous
//
#include <hip/hip_runtime.h>
#include <stdint.h>

// r12/r13/r14 all 198us invariant => per-sample ALU chain is the bottleneck;
// model recalibrated to m07's measured VALU ceiling (103/157 TF = sustained
// ~1.6GHz). Remaining 1.65x gap ~= +40 ops/sample == rotate emitted as
// shl+shr+or. THIS ROUND: force v_alignbit_b32 rotates (single variable),
// plus free trims (drop +tiny, hoist selv compares).
// Transcendentals remain raw-ISA inline asm — libm compile hangs on this pod.
// Math (verified r12-r14, absmax 7.6e-6):
//   i*(o) = argmax_i(logits[o,i]+g1[o,i]); c[o]=2*tanh(2*tanh(weight[o,i*]))
//   y[b,o] = c[o]*x[b,i*]*softmax(logits[o,:]+g2[b,o,:])[i*]
// RNG: JAX partitionable threefry2x32, key(42)=(0,42), kg_j=tf(key,(0,j)),
//   bits[e]=o0^o1 of tf(kg,(0,e)).

__device__ __forceinline__ float fast_log2(float x) {
  float r; asm("v_log_f32 %0, %1" : "=v"(r) : "v"(x)); return r;
}
__device__ __forceinline__ float fast_exp2(float x) {
  float r; asm("v_exp_f32 %0, %1" : "=v"(r) : "v"(x)); return r;
}
__device__ __forceinline__ float fast_tanh(float w) {  // (t-1)/(t+1), t=e^2w
  float t = fast_exp2(w * 2.8853900817779268f);
  return (t - 1.0f) / (t + 1.0f);
}

// rotl via v_alignbit_b32 (1 op): rotl(x,r) = rotr(x,32-r) = alignbit(x,x,32-r)
#if defined(__has_builtin) && __has_builtin(__builtin_amdgcn_alignbit)
__device__ __forceinline__ uint32_t rotl_ab(uint32_t x, int r) {
  return __builtin_amdgcn_alignbit(x, x, 32u - (unsigned)r);
}
#else
__device__ __forceinline__ uint32_t rotl_ab(uint32_t x, int r) {
  uint32_t d;
  asm("v_alignbit_b32 %0, %1, %1, %2" : "=v"(d) : "v"(x), "v"(32u - (unsigned)r));
  return d;
}
#endif

// Fully expanded threefry2x32; rotates forced to alignbit.
__device__ __forceinline__ void threefry2x32(uint32_t k0, uint32_t k1,
                                             uint32_t x0, uint32_t x1,
                                             uint32_t& o0, uint32_t& o1) {
  const uint32_t ks2 = k0 ^ k1 ^ 0x1BD11BDAu;
  x0 += k0; x1 += k1;
#define TF_RND(r) { x0 += x1; x1 = rotl_ab(x1, (r)); x1 ^= x0; }
  TF_RND(13) TF_RND(15) TF_RND(26) TF_RND(6)
  x0 += k1;  x1 += ks2 + 1u;
  TF_RND(17) TF_RND(29) TF_RND(16) TF_RND(24)
  x0 += ks2; x1 += k0 + 2u;
  TF_RND(13) TF_RND(15) TF_RND(26) TF_RND(6)
  x0 += k0;  x1 += k1 + 3u;
  TF_RND(17) TF_RND(29) TF_RND(16) TF_RND(24)
  x0 += k1;  x1 += ks2 + 4u;
  TF_RND(13) TF_RND(15) TF_RND(26) TF_RND(6)
  x0 += ks2; x1 += k0 + 5u;
#undef TF_RND
  o0 = x0; o1 = x1;
}

__device__ __forceinline__ uint32_t tf_bits(uint32_t ka, uint32_t kb, uint32_t e) {
  uint32_t r0, r1;
  threefry2x32(ka, kb, 0u, e, r0, r1);
  return r0 ^ r1;
}

// l2 = log2(max(-log2(u), 1e-37)); u = mantissa-frac (no +tiny: the fmax
// guard handles mantissa==0; ~8 of 67M samples, losing-term ~1e-4 relative)
__device__ __forceinline__ float neglog2_from_bits(uint32_t bits) {
  float f  = __uint_as_float((bits >> 9) | 0x3f800000u) - 1.0f;
  float l1 = fast_log2(f);
  float nl = fmaxf(-l1, 1e-37f);
  return fast_log2(nl);
}

// grid: 2048 blocks = 512 o x 4 bgroups; 256 threads (4 waves); 16 rows/wave.
__global__ __launch_bounds__(256) void k_fused(const float* __restrict__ x,
                                               const float* __restrict__ weight,
                                               const float* __restrict__ logits,
                                               float* __restrict__ out) {
  const int o    = blockIdx.x & 511;
  const int bg   = blockIdx.x >> 9;   // 0..3
  const int tid  = threadIdx.x;
  const int lane = tid & 63;
  const int wid  = tid >> 6;
  const float* lrow = logits + o * 512;

  // subkeys (fold-like split of key(42) = (0,42))
  uint32_t k1a, k1b, k2a, k2b;
  threefry2x32(0u, 42u, 0u, 0u, k1a, k1b);  // kg1 for g1 (OUT,IN)
  threefry2x32(0u, 42u, 0u, 1u, k2a, k2b);  // kg2 for g2 (B,OUT,IN)

  // ---- phase 1 (block-cooperative): i* = argmax_i(logits[o,i] + g1[o,i]) ----
  float v; int idx;
  {
    const uint32_t e0 = (uint32_t)(o * 512 + tid);
    float g1a = fmaf(-0.69314718056f, neglog2_from_bits(tf_bits(k1a, k1b, e0)),
                     0.3665129206f);
    v   = lrow[tid] + g1a;
    idx = tid;
    float g1b = fmaf(-0.69314718056f, neglog2_from_bits(tf_bits(k1a, k1b, e0 + 256u)),
                     0.3665129206f);
    float v2 = lrow[tid + 256] + g1b;
    if (v2 > v) { v = v2; idx = tid + 256; }  // tie -> lower index (jnp.argmax)
  }
  for (int off = 32; off > 0; off >>= 1) {
    float ov = __shfl_down(v, off);
    int   oi = __shfl_down(idx, off);
    if (ov > v || (ov == v && oi < idx)) { v = ov; idx = oi; }
  }
  __shared__ float swv[4];
  __shared__ int   swi[4];
  __shared__ int   s_istar;
  __shared__ float s_c;
  if (lane == 0) { swv[wid] = v; swi[wid] = idx; }
  __syncthreads();
  if (tid == 0) {
    float bv = swv[0]; int bi = swi[0];
    for (int w = 1; w < 4; ++w)
      if (swv[w] > bv || (swv[w] == bv && swi[w] < bi)) { bv = swv[w]; bi = swi[w]; }
    s_istar = bi;
    s_c = 2.0f * fast_tanh(2.0f * fast_tanh(weight[o * 512 + bi]));
  }
  __syncthreads();
  const int   isel = s_istar;
  const float c    = s_c;

  // ---- cache scaled logits (block-constant) in registers ----
  // ev = exp2(lsc[j] - l2), lsc = l*log2e - log2(ln2)
  float lsc0 = fmaf(lrow[lane      ], 1.4426950408889634f, 0.5287663729f);
  float lsc1 = fmaf(lrow[lane +  64], 1.4426950408889634f, 0.5287663729f);
  float lsc2 = fmaf(lrow[lane + 128], 1.4426950408889634f, 0.5287663729f);
  float lsc3 = fmaf(lrow[lane + 192], 1.4426950408889634f, 0.5287663729f);
  float lsc4 = fmaf(lrow[lane + 256], 1.4426950408889634f, 0.5287663729f);
  float lsc5 = fmaf(lrow[lane + 320], 1.4426950408889634f, 0.5287663729f);
  float lsc6 = fmaf(lrow[lane + 384], 1.4426950408889634f, 0.5287663729f);
  float lsc7 = fmaf(lrow[lane + 448], 1.4426950408889634f, 0.5287663729f);

  // hoisted selv masks (loop-invariant across the 16 rows)
  const bool hit0 = (lane       == isel);
  const bool hit1 = (lane +  64 == isel);
  const bool hit2 = (lane + 128 == isel);
  const bool hit3 = (lane + 192 == isel);
  const bool hit4 = (lane + 256 == isel);
  const bool hit5 = (lane + 320 == isel);
  const bool hit6 = (lane + 384 == isel);
  const bool hit7 = (lane + 448 == isel);

  // ---- phase 2: 16 rows per wave ----
  const int b0 = bg * 64 + wid * 16;
#pragma unroll 1
  for (int it = 0; it < 16; ++it) {
    const int b   = b0 + it;                   // 0..255
    const int row = (b << 9) | o;              // 0..131071
    const uint32_t base = (uint32_t)row << 9;  // < 2^26
    const uint32_t elane = base + (uint32_t)lane;

    float sum = 0.0f, selv = 0.0f;
#define G2_SAMPLE(J, LSC, HIT)                                    \
    {                                                             \
      float l2 = neglog2_from_bits(tf_bits(k2a, k2b, elane + 64u * (J))); \
      float ev = fast_exp2((LSC) - l2);                           \
      sum += ev;                                                  \
      selv = (HIT) ? ev : selv;                                   \
    }
    G2_SAMPLE(0, lsc0, hit0) G2_SAMPLE(1, lsc1, hit1)
    G2_SAMPLE(2, lsc2, hit2) G2_SAMPLE(3, lsc3, hit3)
    G2_SAMPLE(4, lsc4, hit4) G2_SAMPLE(5, lsc5, hit5)
    G2_SAMPLE(6, lsc6, hit6) G2_SAMPLE(7, lsc7, hit7)
#undef G2_SAMPLE
    for (int off = 32; off > 0; off >>= 1) sum += __shfl_down(sum, off);
    selv = __shfl(selv, isel & 63);            // exactly one lane holds it
    if (lane == 0) out[row] = c * x[(b << 9) | isel] * selv / sum;
  }
}

extern "C" void kernel_launch(void* const* d_in, const int* in_sizes, int n_in,
                              void* d_out, int out_size, void* d_ws, size_t ws_size,
                              hipStream_t stream) {
  const float* x      = (const float*)d_in[0];
  const float* weight = (const float*)d_in[1];
  const float* logits = (const float*)d_in[2];
  float* out = (float*)d_out;
  k_fused<<<dim3(512 * 4), dim3(256), 0, stream>>>(x, weight, logits, out);
}

// Round 16
// 158.703 us; speedup vs baseline: 1.1444x; 1.1408x over previous
//
#include <hip/hip_runtime.h>
#include <stdint.h>

// r12-r15 all ~198us regardless of structure => per-sample compiled chain is
// invariant bottleneck. Counter arithmetic implies ~150-220 issued slots per
// sample vs ~83 hand-counted. THIS ROUND: remove compiler freedom — the whole
// 20-round threefry (+injections+fold) is ONE 71-instruction inline-asm block
// (v_add_u32 / v_alignbit_b32 / v_xor_b32, keys as constexpr SGPR operands).
// Everything else identical to r15 (passed, absmax 7.6e-6).
// Transcendentals remain raw-ISA asm — libm compile hangs on this pod.

struct U2 { uint32_t a, b; };
constexpr uint32_t crotl(uint32_t x, int r) { return (x << r) | (x >> (32 - r)); }

constexpr U2 ctf(uint32_t k0, uint32_t k1, uint32_t x0, uint32_t x1) {
  const uint32_t ks2 = k0 ^ k1 ^ 0x1BD11BDAu;
  x0 += k0; x1 += k1;
  // G1
  x0 += x1; x1 = crotl(x1, 13); x1 ^= x0;
  x0 += x1; x1 = crotl(x1, 15); x1 ^= x0;
  x0 += x1; x1 = crotl(x1, 26); x1 ^= x0;
  x0 += x1; x1 = crotl(x1, 6);  x1 ^= x0;
  x0 += k1;  x1 += ks2 + 1u;
  // G2
  x0 += x1; x1 = crotl(x1, 17); x1 ^= x0;
  x0 += x1; x1 = crotl(x1, 29); x1 ^= x0;
  x0 += x1; x1 = crotl(x1, 16); x1 ^= x0;
  x0 += x1; x1 = crotl(x1, 24); x1 ^= x0;
  x0 += ks2; x1 += k0 + 2u;
  // G3
  x0 += x1; x1 = crotl(x1, 13); x1 ^= x0;
  x0 += x1; x1 = crotl(x1, 15); x1 ^= x0;
  x0 += x1; x1 = crotl(x1, 26); x1 ^= x0;
  x0 += x1; x1 = crotl(x1, 6);  x1 ^= x0;
  x0 += k0;  x1 += k1 + 3u;
  // G4
  x0 += x1; x1 = crotl(x1, 17); x1 ^= x0;
  x0 += x1; x1 = crotl(x1, 29); x1 ^= x0;
  x0 += x1; x1 = crotl(x1, 16); x1 ^= x0;
  x0 += x1; x1 = crotl(x1, 24); x1 ^= x0;
  x0 += k1;  x1 += ks2 + 4u;
  // G5
  x0 += x1; x1 = crotl(x1, 13); x1 ^= x0;
  x0 += x1; x1 = crotl(x1, 15); x1 ^= x0;
  x0 += x1; x1 = crotl(x1, 26); x1 ^= x0;
  x0 += x1; x1 = crotl(x1, 6);  x1 ^= x0;
  x0 += ks2; x1 += k0 + 5u;
  return U2{x0, x1};
}

// subkeys (fold-like split of key(42) = (0,42)) — compile-time constants
constexpr U2 KG1 = ctf(0u, 42u, 0u, 0u);   // g1 (OUT,IN)
constexpr U2 KG2 = ctf(0u, 42u, 0u, 1u);   // g2 (B,OUT,IN)
constexpr uint32_t K0  = KG2.a, K1 = KG2.b;
constexpr uint32_t KS2 = K0 ^ K1 ^ 0x1BD11BDAu;
constexpr uint32_t C1 = KS2 + 1u, C2 = K0 + 2u, C3 = K1 + 3u,
                   C4 = KS2 + 4u, C5 = K0 + 5u;

// Entire keyed threefry (x0=0 init folded; x1 input must be e + K1):
// exactly 71 instructions, returns o0^o1.
__device__ __forceinline__ uint32_t tf20_bits(uint32_t x1) {
  uint32_t x0;
  asm("v_add_u32 %0, %2, %1\n"        // R1 add (x0 = K0 + x1)
      "v_alignbit_b32 %1, %1, %1, 19\n"
      "v_xor_b32 %1, %1, %0\n"
      "v_add_u32 %0, %0, %1\n"        // R2
      "v_alignbit_b32 %1, %1, %1, 17\n"
      "v_xor_b32 %1, %1, %0\n"
      "v_add_u32 %0, %0, %1\n"        // R3
      "v_alignbit_b32 %1, %1, %1, 6\n"
      "v_xor_b32 %1, %1, %0\n"
      "v_add_u32 %0, %0, %1\n"        // R4
      "v_alignbit_b32 %1, %1, %1, 26\n"
      "v_xor_b32 %1, %1, %0\n"
      "v_add_u32 %0, %3, %0\n"        // x0 += K1
      "v_add_u32 %1, %5, %1\n"        // x1 += KS2+1
      "v_add_u32 %0, %0, %1\n"        // R5
      "v_alignbit_b32 %1, %1, %1, 15\n"
      "v_xor_b32 %1, %1, %0\n"
      "v_add_u32 %0, %0, %1\n"        // R6
      "v_alignbit_b32 %1, %1, %1, 3\n"
      "v_xor_b32 %1, %1, %0\n"
      "v_add_u32 %0, %0, %1\n"        // R7
      "v_alignbit_b32 %1, %1, %1, 16\n"
      "v_xor_b32 %1, %1, %0\n"
      "v_add_u32 %0, %0, %1\n"        // R8
      "v_alignbit_b32 %1, %1, %1, 8\n"
      "v_xor_b32 %1, %1, %0\n"
      "v_add_u32 %0, %4, %0\n"        // x0 += KS2
      "v_add_u32 %1, %6, %1\n"        // x1 += K0+2
      "v_add_u32 %0, %0, %1\n"        // R9
      "v_alignbit_b32 %1, %1, %1, 19\n"
      "v_xor_b32 %1, %1, %0\n"
      "v_add_u32 %0, %0, %1\n"        // R10
      "v_alignbit_b32 %1, %1, %1, 17\n"
      "v_xor_b32 %1, %1, %0\n"
      "v_add_u32 %0, %0, %1\n"        // R11
      "v_alignbit_b32 %1, %1, %1, 6\n"
      "v_xor_b32 %1, %1, %0\n"
      "v_add_u32 %0, %0, %1\n"        // R12
      "v_alignbit_b32 %1, %1, %1, 26\n"
      "v_xor_b32 %1, %1, %0\n"
      "v_add_u32 %0, %2, %0\n"        // x0 += K0
      "v_add_u32 %1, %7, %1\n"        // x1 += K1+3
      "v_add_u32 %0, %0, %1\n"        // R13
      "v_alignbit_b32 %1, %1, %1, 15\n"
      "v_xor_b32 %1, %1, %0\n"
      "v_add_u32 %0, %0, %1\n"        // R14
      "v_alignbit_b32 %1, %1, %1, 3\n"
      "v_xor_b32 %1, %1, %0\n"
      "v_add_u32 %0, %0, %1\n"        // R15
      "v_alignbit_b32 %1, %1, %1, 16\n"
      "v_xor_b32 %1, %1, %0\n"
      "v_add_u32 %0, %0, %1\n"        // R16
      "v_alignbit_b32 %1, %1, %1, 8\n"
      "v_xor_b32 %1, %1, %0\n"
      "v_add_u32 %0, %3, %0\n"        // x0 += K1
      "v_add_u32 %1, %8, %1\n"        // x1 += KS2+4
      "v_add_u32 %0, %0, %1\n"        // R17
      "v_alignbit_b32 %1, %1, %1, 19\n"
      "v_xor_b32 %1, %1, %0\n"
      "v_add_u32 %0, %0, %1\n"        // R18
      "v_alignbit_b32 %1, %1, %1, 17\n"
      "v_xor_b32 %1, %1, %0\n"
      "v_add_u32 %0, %0, %1\n"        // R19
      "v_alignbit_b32 %1, %1, %1, 6\n"
      "v_xor_b32 %1, %1, %0\n"
      "v_add_u32 %0, %0, %1\n"        // R20
      "v_alignbit_b32 %1, %1, %1, 26\n"
      "v_xor_b32 %1, %1, %0\n"
      "v_add_u32 %0, %4, %0\n"        // x0 += KS2
      "v_add_u32 %1, %9, %1\n"        // x1 += K0+5
      "v_xor_b32 %1, %1, %0\n"        // fold: bits = o0^o1
      : "=&v"(x0), "+v"(x1)
      : "s"(K0), "s"(K1), "s"(KS2), "s"(C1), "s"(C2), "s"(C3), "s"(C4), "s"(C5));
  return x1;
}

__device__ __forceinline__ float fast_log2(float x) {
  float r; asm("v_log_f32 %0, %1" : "=v"(r) : "v"(x)); return r;
}
__device__ __forceinline__ float fast_exp2(float x) {
  float r; asm("v_exp_f32 %0, %1" : "=v"(r) : "v"(x)); return r;
}
__device__ __forceinline__ float fast_tanh(float w) {  // (t-1)/(t+1), t=e^2w
  float t = fast_exp2(w * 2.8853900817779268f);
  return (t - 1.0f) / (t + 1.0f);
}

// C threefry for the cold g1 path (2 calls/thread) — keys KG1.
__device__ __forceinline__ uint32_t rotl(uint32_t x, int r) {
  return __builtin_rotateleft32(x, (unsigned)r);
}
__device__ __forceinline__ uint32_t tf_bits_g1(uint32_t e) {
  const uint32_t k0 = KG1.a, k1 = KG1.b;
  const uint32_t ks2 = k0 ^ k1 ^ 0x1BD11BDAu;
  uint32_t x0 = k0, x1 = e + k1;
#define TF_RND(r) { x0 += x1; x1 = rotl(x1, (r)); x1 ^= x0; }
  TF_RND(13) TF_RND(15) TF_RND(26) TF_RND(6)
  x0 += k1;  x1 += ks2 + 1u;
  TF_RND(17) TF_RND(29) TF_RND(16) TF_RND(24)
  x0 += ks2; x1 += k0 + 2u;
  TF_RND(13) TF_RND(15) TF_RND(26) TF_RND(6)
  x0 += k0;  x1 += k1 + 3u;
  TF_RND(17) TF_RND(29) TF_RND(16) TF_RND(24)
  x0 += k1;  x1 += ks2 + 4u;
  TF_RND(13) TF_RND(15) TF_RND(26) TF_RND(6)
  x0 += ks2; x1 += k0 + 5u;
#undef TF_RND
  return x0 ^ x1;
}

// l2 = log2(max(-log2(u), 1e-37)); u = mantissa-frac (fmax guards u==0 case)
__device__ __forceinline__ float neglog2_from_bits(uint32_t bits) {
  float f  = __uint_as_float((bits >> 9) | 0x3f800000u) - 1.0f;
  float l1 = fast_log2(f);
  float nl = fmaxf(-l1, 1e-37f);
  return fast_log2(nl);
}

// grid: 2048 blocks = 512 o x 4 bgroups; 256 threads (4 waves); 16 rows/wave.
__global__ __launch_bounds__(256) void k_fused(const float* __restrict__ x,
                                               const float* __restrict__ weight,
                                               const float* __restrict__ logits,
                                               float* __restrict__ out) {
  const int o    = blockIdx.x & 511;
  const int bg   = blockIdx.x >> 9;   // 0..3
  const int tid  = threadIdx.x;
  const int lane = tid & 63;
  const int wid  = tid >> 6;
  const float* lrow = logits + o * 512;

  // ---- phase 1 (block-cooperative): i* = argmax_i(logits[o,i] + g1[o,i]) ----
  float v; int idx;
  {
    const uint32_t e0 = (uint32_t)(o * 512 + tid);
    float g1a = fmaf(-0.69314718056f, neglog2_from_bits(tf_bits_g1(e0)),
                     0.3665129206f);
    v   = lrow[tid] + g1a;
    idx = tid;
    float g1b = fmaf(-0.69314718056f, neglog2_from_bits(tf_bits_g1(e0 + 256u)),
                     0.3665129206f);
    float v2 = lrow[tid + 256] + g1b;
    if (v2 > v) { v = v2; idx = tid + 256; }  // tie -> lower index (jnp.argmax)
  }
  for (int off = 32; off > 0; off >>= 1) {
    float ov = __shfl_down(v, off);
    int   oi = __shfl_down(idx, off);
    if (ov > v || (ov == v && oi < idx)) { v = ov; idx = oi; }
  }
  __shared__ float swv[4];
  __shared__ int   swi[4];
  __shared__ int   s_istar;
  __shared__ float s_c;
  if (lane == 0) { swv[wid] = v; swi[wid] = idx; }
  __syncthreads();
  if (tid == 0) {
    float bv = swv[0]; int bi = swi[0];
    for (int w = 1; w < 4; ++w)
      if (swv[w] > bv || (swv[w] == bv && swi[w] < bi)) { bv = swv[w]; bi = swi[w]; }
    s_istar = bi;
    s_c = 2.0f * fast_tanh(2.0f * fast_tanh(weight[o * 512 + bi]));
  }
  __syncthreads();
  const int   isel = s_istar;
  const float c    = s_c;

  // ---- cache scaled logits (block-constant) in registers ----
  float lsc0 = fmaf(lrow[lane      ], 1.4426950408889634f, 0.5287663729f);
  float lsc1 = fmaf(lrow[lane +  64], 1.4426950408889634f, 0.5287663729f);
  float lsc2 = fmaf(lrow[lane + 128], 1.4426950408889634f, 0.5287663729f);
  float lsc3 = fmaf(lrow[lane + 192], 1.4426950408889634f, 0.5287663729f);
  float lsc4 = fmaf(lrow[lane + 256], 1.4426950408889634f, 0.5287663729f);
  float lsc5 = fmaf(lrow[lane + 320], 1.4426950408889634f, 0.5287663729f);
  float lsc6 = fmaf(lrow[lane + 384], 1.4426950408889634f, 0.5287663729f);
  float lsc7 = fmaf(lrow[lane + 448], 1.4426950408889634f, 0.5287663729f);

  const bool hit0 = (lane       == isel);
  const bool hit1 = (lane +  64 == isel);
  const bool hit2 = (lane + 128 == isel);
  const bool hit3 = (lane + 192 == isel);
  const bool hit4 = (lane + 256 == isel);
  const bool hit5 = (lane + 320 == isel);
  const bool hit6 = (lane + 384 == isel);
  const bool hit7 = (lane + 448 == isel);

  // ---- phase 2: 16 rows per wave ----
  const int b0 = bg * 64 + wid * 16;
#pragma unroll 1
  for (int it = 0; it < 16; ++it) {
    const int b   = b0 + it;                   // 0..255
    const int row = (b << 9) | o;              // 0..131071
    const uint32_t base = (uint32_t)row << 9;  // < 2^26
    // x1 init for tf20: e + K1, with e = base + lane + 64*J
    const uint32_t ekrow = base + (uint32_t)lane + K1;

    float sum = 0.0f, selv = 0.0f;
#define G2_SAMPLE(J, LSC, HIT)                                    \
    {                                                             \
      float l2 = neglog2_from_bits(tf20_bits(ekrow + 64u * (J))); \
      float ev = fast_exp2((LSC) - l2);                           \
      sum += ev;                                                  \
      selv = (HIT) ? ev : selv;                                   \
    }
    G2_SAMPLE(0, lsc0, hit0) G2_SAMPLE(1, lsc1, hit1)
    G2_SAMPLE(2, lsc2, hit2) G2_SAMPLE(3, lsc3, hit3)
    G2_SAMPLE(4, lsc4, hit4) G2_SAMPLE(5, lsc5, hit5)
    G2_SAMPLE(6, lsc6, hit6) G2_SAMPLE(7, lsc7, hit7)
#undef G2_SAMPLE
    for (int off = 32; off > 0; off >>= 1) sum += __shfl_down(sum, off);
    selv = __shfl(selv, isel & 63);            // exactly one lane holds it
    if (lane == 0) out[row] = c * x[(b << 9) | isel] * selv / sum;
  }
}

extern "C" void kernel_launch(void* const* d_in, const int* in_sizes, int n_in,
                              void* d_out, int out_size, void* d_ws, size_t ws_size,
                              hipStream_t stream) {
  const float* x      = (const float*)d_in[0];
  const float* weight = (const float*)d_in[1];
  const float* logits = (const float*)d_in[2];
  float* out = (float*)d_out;
  k_fused<<<dim3(512 * 4), dim3(256), 0, stream>>>(x, weight, logits, out);
}

// Round 17
// 154.369 us; speedup vs baseline: 1.1765x; 1.0281x over previous
//
#include <hip/hip_runtime.h>
#include <stdint.h>

// r16: monolithic 71-instr asm threefry -> 198->172us. Still ~2x above issue
// floor; VALUBusy-95% may be gfx94x-formula overread (2x) => latency/ILP
// suspect. THIS ROUND: (1) dual-chain interleaved asm threefry (dep distance
// 2) as the latency discriminator; (2) rcp trick: ev = el_j * rcp(-log2 u),
// el_j = exp2(lsc_j) block-constant (kills exp2+fmax+sub per sample).
// g1/argmax path byte-identical to r16 (passed, absmax 7.6e-6).
// All transcendentals raw-ISA asm — libm compile hangs on this pod.

struct U2 { uint32_t a, b; };
constexpr uint32_t crotl(uint32_t x, int r) { return (x << r) | (x >> (32 - r)); }

constexpr U2 ctf(uint32_t k0, uint32_t k1, uint32_t x0, uint32_t x1) {
  const uint32_t ks2 = k0 ^ k1 ^ 0x1BD11BDAu;
  x0 += k0; x1 += k1;
  x0 += x1; x1 = crotl(x1, 13); x1 ^= x0;
  x0 += x1; x1 = crotl(x1, 15); x1 ^= x0;
  x0 += x1; x1 = crotl(x1, 26); x1 ^= x0;
  x0 += x1; x1 = crotl(x1, 6);  x1 ^= x0;
  x0 += k1;  x1 += ks2 + 1u;
  x0 += x1; x1 = crotl(x1, 17); x1 ^= x0;
  x0 += x1; x1 = crotl(x1, 29); x1 ^= x0;
  x0 += x1; x1 = crotl(x1, 16); x1 ^= x0;
  x0 += x1; x1 = crotl(x1, 24); x1 ^= x0;
  x0 += ks2; x1 += k0 + 2u;
  x0 += x1; x1 = crotl(x1, 13); x1 ^= x0;
  x0 += x1; x1 = crotl(x1, 15); x1 ^= x0;
  x0 += x1; x1 = crotl(x1, 26); x1 ^= x0;
  x0 += x1; x1 = crotl(x1, 6);  x1 ^= x0;
  x0 += k0;  x1 += k1 + 3u;
  x0 += x1; x1 = crotl(x1, 17); x1 ^= x0;
  x0 += x1; x1 = crotl(x1, 29); x1 ^= x0;
  x0 += x1; x1 = crotl(x1, 16); x1 ^= x0;
  x0 += x1; x1 = crotl(x1, 24); x1 ^= x0;
  x0 += k1;  x1 += ks2 + 4u;
  x0 += x1; x1 = crotl(x1, 13); x1 ^= x0;
  x0 += x1; x1 = crotl(x1, 15); x1 ^= x0;
  x0 += x1; x1 = crotl(x1, 26); x1 ^= x0;
  x0 += x1; x1 = crotl(x1, 6);  x1 ^= x0;
  x0 += ks2; x1 += k0 + 5u;
  return U2{x0, x1};
}

constexpr U2 KG1 = ctf(0u, 42u, 0u, 0u);   // g1 (OUT,IN)
constexpr U2 KG2 = ctf(0u, 42u, 0u, 1u);   // g2 (B,OUT,IN)
constexpr uint32_t K0  = KG2.a, K1 = KG2.b;
constexpr uint32_t KS2 = K0 ^ K1 ^ 0x1BD11BDAu;
constexpr uint32_t C1 = KS2 + 1u, C2 = K0 + 2u, C3 = K1 + 3u,
                   C4 = KS2 + 4u, C5 = K0 + 5u;

// one threefry round for both chains, interleaved (shift S = 32 - rot)
#define TFR2(S) \
  "v_add_u32 %0,%0,%1\n\t" "v_add_u32 %2,%2,%3\n\t" \
  "v_alignbit_b32 %1,%1,%1," S "\n\t" "v_alignbit_b32 %3,%3,%3," S "\n\t" \
  "v_xor_b32 %1,%1,%0\n\t" "v_xor_b32 %3,%3,%2\n\t"
// key injection for both chains: x0 += KA ; x1 += KB
#define INJ2(KA, KB) \
  "v_add_u32 %0," KA ",%0\n\t" "v_add_u32 %2," KA ",%2\n\t" \
  "v_add_u32 %1," KB ",%1\n\t" "v_add_u32 %3," KB ",%3\n\t"

// Dual keyed threefry (keys KG2), x1 inputs pre-offset by +K1; returns folded
// bits for both chains. Bit-exact to r16's verified single-chain version.
__device__ __forceinline__ void tf20x2(uint32_t x1a, uint32_t x1b,
                                       uint32_t& ba, uint32_t& bb) {
  uint32_t x0a, x0b;
  asm(// R1 with x0-init fold: x0 = K0 + x1
      "v_add_u32 %0,%4,%1\n\t" "v_add_u32 %2,%4,%3\n\t"
      "v_alignbit_b32 %1,%1,%1,19\n\t" "v_alignbit_b32 %3,%3,%3,19\n\t"
      "v_xor_b32 %1,%1,%0\n\t" "v_xor_b32 %3,%3,%2\n\t"
      TFR2("17") TFR2("6") TFR2("26")        // R2-R4 (rot 15,26,6)
      INJ2("%5", "%7")                        // += (K1, KS2+1)
      TFR2("15") TFR2("3") TFR2("16") TFR2("8")   // R5-R8 (rot 17,29,16,24)
      INJ2("%6", "%8")                        // += (KS2, K0+2)
      TFR2("19") TFR2("17") TFR2("6") TFR2("26")  // R9-R12 (rot 13,15,26,6)
      INJ2("%4", "%9")                        // += (K0, K1+3)
      TFR2("15") TFR2("3") TFR2("16") TFR2("8")   // R13-R16
      INJ2("%5", "%10")                       // += (K1, KS2+4)
      TFR2("19") TFR2("17") TFR2("6") TFR2("26")  // R17-R20
      INJ2("%6", "%11")                       // += (KS2, K0+5)
      "v_xor_b32 %1,%1,%0\n\t" "v_xor_b32 %3,%3,%2\n\t"  // fold o0^o1
      : "=&v"(x0a), "+v"(x1a), "=&v"(x0b), "+v"(x1b)
      : "s"(K0), "s"(K1), "s"(KS2), "s"(C1), "s"(C2), "s"(C3), "s"(C4), "s"(C5));
  ba = x1a; bb = x1b;
}

__device__ __forceinline__ float fast_log2(float x) {
  float r; asm("v_log_f32 %0, %1" : "=v"(r) : "v"(x)); return r;
}
__device__ __forceinline__ float fast_exp2(float x) {
  float r; asm("v_exp_f32 %0, %1" : "=v"(r) : "v"(x)); return r;
}
// 1/(-x), negation folded into the rcp source modifier
#if defined(__has_builtin) && __has_builtin(__builtin_amdgcn_rcpf)
__device__ __forceinline__ float rcp_neg(float x) {
  return __builtin_amdgcn_rcpf(-x);
}
#else
__device__ __forceinline__ float rcp_neg(float x) {
  float r; asm("v_rcp_f32_e64 %0, -%1" : "=v"(r) : "v"(x)); return r;
}
#endif
__device__ __forceinline__ float fast_tanh(float w) {  // (t-1)/(t+1), t=e^2w
  float t = fast_exp2(w * 2.8853900817779268f);
  return (t - 1.0f) / (t + 1.0f);
}

// ---- g1 path (cold, 2 calls/thread) — byte-identical to r16 ----
__device__ __forceinline__ uint32_t rotl(uint32_t x, int r) {
  return __builtin_rotateleft32(x, (unsigned)r);
}
__device__ __forceinline__ uint32_t tf_bits_g1(uint32_t e) {
  const uint32_t k0 = KG1.a, k1 = KG1.b;
  const uint32_t ks2 = k0 ^ k1 ^ 0x1BD11BDAu;
  uint32_t x0 = k0, x1 = e + k1;
#define TF_RND(r) { x0 += x1; x1 = rotl(x1, (r)); x1 ^= x0; }
  TF_RND(13) TF_RND(15) TF_RND(26) TF_RND(6)
  x0 += k1;  x1 += ks2 + 1u;
  TF_RND(17) TF_RND(29) TF_RND(16) TF_RND(24)
  x0 += ks2; x1 += k0 + 2u;
  TF_RND(13) TF_RND(15) TF_RND(26) TF_RND(6)
  x0 += k0;  x1 += k1 + 3u;
  TF_RND(17) TF_RND(29) TF_RND(16) TF_RND(24)
  x0 += k1;  x1 += ks2 + 4u;
  TF_RND(13) TF_RND(15) TF_RND(26) TF_RND(6)
  x0 += ks2; x1 += k0 + 5u;
#undef TF_RND
  return x0 ^ x1;
}
__device__ __forceinline__ float neglog2_from_bits(uint32_t bits) {
  float f  = __uint_as_float((bits >> 9) | 0x3f800000u) - 1.0f;
  float l1 = fast_log2(f);
  float nl = fmaxf(-l1, 1e-37f);
  return fast_log2(nl);
}

// grid: 2048 blocks = 512 o x 4 bgroups; 256 threads (4 waves); 16 rows/wave.
__global__ __launch_bounds__(256) void k_fused(const float* __restrict__ x,
                                               const float* __restrict__ weight,
                                               const float* __restrict__ logits,
                                               float* __restrict__ out) {
  const int o    = blockIdx.x & 511;
  const int bg   = blockIdx.x >> 9;   // 0..3
  const int tid  = threadIdx.x;
  const int lane = tid & 63;
  const int wid  = tid >> 6;
  const float* lrow = logits + o * 512;

  // ---- phase 1 (block-cooperative): i* = argmax_i(logits[o,i] + g1[o,i]) ----
  float v; int idx;
  {
    const uint32_t e0 = (uint32_t)(o * 512 + tid);
    float g1a = fmaf(-0.69314718056f, neglog2_from_bits(tf_bits_g1(e0)),
                     0.3665129206f);
    v   = lrow[tid] + g1a;
    idx = tid;
    float g1b = fmaf(-0.69314718056f, neglog2_from_bits(tf_bits_g1(e0 + 256u)),
                     0.3665129206f);
    float v2 = lrow[tid + 256] + g1b;
    if (v2 > v) { v = v2; idx = tid + 256; }  // tie -> lower index (jnp.argmax)
  }
  for (int off = 32; off > 0; off >>= 1) {
    float ov = __shfl_down(v, off);
    int   oi = __shfl_down(idx, off);
    if (ov > v || (ov == v && oi < idx)) { v = ov; idx = oi; }
  }
  __shared__ float swv[4];
  __shared__ int   swi[4];
  __shared__ int   s_istar;
  __shared__ float s_c;
  if (lane == 0) { swv[wid] = v; swi[wid] = idx; }
  __syncthreads();
  if (tid == 0) {
    float bv = swv[0]; int bi = swi[0];
    for (int w = 1; w < 4; ++w)
      if (swv[w] > bv || (swv[w] == bv && swi[w] < bi)) { bv = swv[w]; bi = swi[w]; }
    s_istar = bi;
    s_c = 2.0f * fast_tanh(2.0f * fast_tanh(weight[o * 512 + bi]));
  }
  __syncthreads();
  const int   isel = s_istar;
  const float c    = s_c;

  // ---- block-constant per-sample scale: el_j = exp2(lsc_j) ----
  // ev = exp(logit+g2) = el_j * rcp(-log2 u);  lsc = l*log2e + log2(1/ln2)
  const float LOG2E = 1.4426950408889634f, CADD = 0.5287663729f;
  float el0 = fast_exp2(fmaf(lrow[lane      ], LOG2E, CADD));
  float el1 = fast_exp2(fmaf(lrow[lane +  64], LOG2E, CADD));
  float el2 = fast_exp2(fmaf(lrow[lane + 128], LOG2E, CADD));
  float el3 = fast_exp2(fmaf(lrow[lane + 192], LOG2E, CADD));
  float el4 = fast_exp2(fmaf(lrow[lane + 256], LOG2E, CADD));
  float el5 = fast_exp2(fmaf(lrow[lane + 320], LOG2E, CADD));
  float el6 = fast_exp2(fmaf(lrow[lane + 384], LOG2E, CADD));
  float el7 = fast_exp2(fmaf(lrow[lane + 448], LOG2E, CADD));

  const bool hit0 = (lane       == isel);
  const bool hit1 = (lane +  64 == isel);
  const bool hit2 = (lane + 128 == isel);
  const bool hit3 = (lane + 192 == isel);
  const bool hit4 = (lane + 256 == isel);
  const bool hit5 = (lane + 320 == isel);
  const bool hit6 = (lane + 384 == isel);
  const bool hit7 = (lane + 448 == isel);

  // ---- phase 2: 16 rows per wave, samples processed in dual-chain pairs ----
  const int b0 = bg * 64 + wid * 16;
#pragma unroll 1
  for (int it = 0; it < 16; ++it) {
    const int b   = b0 + it;                   // 0..255
    const int row = (b << 9) | o;              // 0..131071
    const uint32_t base = (uint32_t)row << 9;  // < 2^26
    const uint32_t ekrow = base + (uint32_t)lane + K1;  // x1 init = e + K1

    float sum = 0.0f, selv = 0.0f;
#define G2_PAIR(JA, ELA, HA, ELB, HB)                                \
    {                                                                \
      uint32_t bA, bB;                                               \
      tf20x2(ekrow + 128u * (JA), ekrow + 128u * (JA) + 64u, bA, bB);\
      float fA = __uint_as_float((bA >> 9) | 0x3f800000u) - 1.0f;    \
      float fB = __uint_as_float((bB >> 9) | 0x3f800000u) - 1.0f;    \
      float evA = (ELA) * rcp_neg(fast_log2(fA));                    \
      float evB = (ELB) * rcp_neg(fast_log2(fB));                    \
      sum += evA; selv = (HA) ? evA : selv;                          \
      sum += evB; selv = (HB) ? evB : selv;                          \
    }
    G2_PAIR(0, el0, hit0, el1, hit1)
    G2_PAIR(1, el2, hit2, el3, hit3)
    G2_PAIR(2, el4, hit4, el5, hit5)
    G2_PAIR(3, el6, hit6, el7, hit7)
#undef G2_PAIR
    for (int off = 32; off > 0; off >>= 1) sum += __shfl_down(sum, off);
    selv = __shfl(selv, isel & 63);            // exactly one lane holds it
    if (lane == 0) out[row] = c * x[(b << 9) | isel] * selv / sum;
  }
}

extern "C" void kernel_launch(void* const* d_in, const int* in_sizes, int n_in,
                              void* d_out, int out_size, void* d_ws, size_t ws_size,
                              hipStream_t stream) {
  const float* x      = (const float*)d_in[0];
  const float* weight = (const float*)d_in[1];
  const float* logits = (const float*)d_in[2];
  float* out = (float*)d_out;
  k_fused<<<dim3(512 * 4), dim3(256), 0, stream>>>(x, weight, logits, out);
}